// Round 7
// baseline (122.753 us; speedup 1.0000x reference)
//
#include <hip/hip_runtime.h>
#include <hip/hip_bf16.h>

// Problem constants
#define BATCH 4
#define S_TOT 4096
#define ROWS (BATCH * S_TOT)   // 16384
#define DM 2048
#define DSP 128
#define NSEG 512               // neurons per segment; 3 segments

typedef short short8 __attribute__((ext_vector_type(8)));
typedef float f32x16 __attribute__((ext_vector_type(16)));

// float -> bf16(RNE) bits; also returns the fp32 value of the bf16 for residual
static __device__ inline short f2bf(float v, float& back) {
  unsigned u = __float_as_uint(v);
  unsigned r = u + 0x7FFFu + ((u >> 16) & 1u);
  unsigned short hs = (unsigned short)(r >> 16);
  back = __uint_as_float(((unsigned)hs) << 16);
  return (short)hs;
}

// packed f32x2 -> bf16x2 (hw instruction). Rounding mode irrelevant for the
// split scheme: lo is computed as exact residual vs the value hi rounded to.
static __device__ inline unsigned cvtpk2(float a, float b) {
  unsigned r;
  asm("v_cvt_pk_bf16_f32 %0, %1, %2" : "=v"(r) : "v"(a), "v"(b));
  return r;
}
// 8 fp32 -> hi/lo bf16 short8 (3 VALU/elem vs ~10 for scalar f2bf)
static __device__ inline void cvt8(const float* v, short8& hi8, short8& lo8) {
  union { short8 s; unsigned u[4]; } H, L;
  #pragma unroll
  for (int w = 0; w < 4; ++w) {
    const float f0 = v[2 * w], f1 = v[2 * w + 1];
    const unsigned u = cvtpk2(f0, f1);
    const float b0 = __uint_as_float(u << 16);
    const float b1 = __uint_as_float(u & 0xffff0000u);
    L.u[w] = cvtpk2(f0 - b0, f1 - b1);
    H.u[w] = u;
  }
  hi8 = H.s; lo8 = L.s;
}

// global_load_lds, 16B per lane: per-lane global src, wave-uniform LDS dst
#define GLL16(gsrc, ldst)                                                       \
  __builtin_amdgcn_global_load_lds(                                             \
      (const __attribute__((address_space(1))) void*)(gsrc),                    \
      (__attribute__((address_space(3))) void*)(ldst), 16, 0, 0)

// Fragment layout for a [R][128-k] matrix, per split:
//   short8 index = rowblk*512 + kchunk*64 + lane,  lane=(row&31)+32*((k>>3)&1)
// For W (B-operand, [128 n][2048 k]): short8 index = (tile*128 + kchunk)*64 + lane,
//   lane=(n&31)+32*((k>>3)&1), tile=n>>5.

// ---------------- K0 fused: W-split pack (blocks 0..511) + emb norm pack -------
__global__ __launch_bounds__(64) void k0_prep(const float* __restrict__ W,
                                              const float* __restrict__ emb,
                                              short* __restrict__ wHi,
                                              short* __restrict__ wLo,
                                              short* __restrict__ eHi,
                                              short* __restrict__ eLo) {
  const int l = threadIdx.x;
  if (blockIdx.x < 512) {
    // pack W: blockIdx = tile*128 + kchunk
    const int tc = blockIdx.x;
    const int t = tc >> 7, c = tc & 127;
    const int n = t * 32 + (l & 31);
    const int k = c * 16 + (l >> 5) * 8;
    const float4 a0 = *(const float4*)&W[(size_t)n * DM + k];
    const float4 a1 = *(const float4*)&W[(size_t)n * DM + k + 4];
    const float av[8] = {a0.x, a0.y, a0.z, a0.w, a1.x, a1.y, a1.z, a1.w};
    short8 hi8, lo8; float bk;
    #pragma unroll
    for (int e = 0; e < 8; ++e) {
      hi8[e] = f2bf(av[e], bk); lo8[e] = f2bf(av[e] - bk, bk);
    }
    const size_t idx = (size_t)tc * 64 + l;
    ((short8*)wHi)[idx] = hi8;
    ((short8*)wLo)[idx] = lo8;
  } else {
    // normalize + pack one emb row
    const int row = blockIdx.x - 512;          // 0..1535
    __shared__ short sh[128], sl[128];
    float2 v = *(const float2*)&emb[row * 128 + l * 2];
    float ss = v.x * v.x + v.y * v.y;
    #pragma unroll
    for (int m = 32; m; m >>= 1) ss += __shfl_xor(ss, m);
    const float inv = 1.0f / fmaxf(sqrtf(ss), 1e-12f);
    float bk;
    const float ox = v.x * inv, oy = v.y * inv;
    sh[2 * l] = f2bf(ox, bk);     sl[2 * l] = f2bf(ox - bk, bk);
    sh[2 * l + 1] = f2bf(oy, bk); sl[2 * l + 1] = f2bf(oy - bk, bk);
    __syncthreads();
    if (l < 32) {
      const int split = l >> 4, kc = (l >> 1) & 7, kh = l & 1;
      const short* src = (split ? sl : sh) + kc * 16 + kh * 8;
      const short8 val = *(const short8*)src;
      const size_t idx = (size_t)(row >> 5) * 4096 + kc * 512 +
                         ((row & 31) + 32 * kh) * 8;
      *(short8*)((split ? eLo : eHi) + idx) = val;
    }
  }
}

// ---------------- K1: h = x @ W^T + b, BM=64 BN=128 full-K, GLL staging --------
// grid 256 (64-row tiles), 512 threads = 8 waves = 2 row-groups x 4 col-tiles.
// Each wave owns a 32x32 output tile over full K (no cross-wave reduction).
// A staged fp32 via global_load_lds (linear dst, XOR-permuted src granules,
// XOR on ds_read); B from packed wHi/wLo (L2). W-traffic: 256 blocks x 1 MB.
__global__ __launch_bounds__(512, 2) void k1_fused(const float* __restrict__ x,
                                                   const short* __restrict__ wHi,
                                                   const short* __restrict__ wLo,
                                                   const float* __restrict__ bias,
                                                   short* __restrict__ hHi,
                                                   short* __restrict__ hLo) {
  __shared__ __align__(16) float As[2][64][128];   // 64 KB staging (dbuf)
  __shared__ float bsh[128];
  const int t = threadIdx.x;
  const int wave = t >> 6, lane = t & 63;
  const int fr = lane & 31, ks = lane >> 5;
  const int rg = wave >> 2, wc = wave & 3;   // row-group, col-tile
  const int m0 = blockIdx.x * 64;

  if (t < 128) bsh[t] = bias[t];

  // Staging: instr (wave, j in 0..3) stages rows 8w+2j+{0,1}; lane ks picks row,
  // lane fr the 16B granule. src granule = fr ^ ((2j+ks)&7); dst linear.
  const float* xs[4];
  #pragma unroll
  for (int j = 0; j < 4; ++j) {
    const int r = 8 * wave + 2 * j + ks;
    xs[j] = x + (size_t)(m0 + r) * DM + ((fr ^ (2 * j + ks)) << 2);
  }
  float* AsF = &As[0][0][0];                 // 8192 floats per buffer

  const short8* bhB = (const short8*)wHi + (size_t)(wc * 128) * 64 + lane;
  const short8* blB = (const short8*)wLo + (size_t)(wc * 128) * 64 + lane;

  f32x16 acc = {};

  #define STAGE(buf, step)                                                      \
    _Pragma("unroll")                                                           \
    for (int j = 0; j < 4; ++j)                                                 \
      GLL16(xs[j] + (step) * 128, AsF + (buf) * 8192 + (8 * wave + 2 * j) * 128);

  STAGE(0, 0);
  __syncthreads();

  #pragma unroll 1
  for (int step = 0; step < 16; ++step) {
    const int buf = step & 1;
    if (step + 1 < 16) STAGE(buf ^ 1, step + 1);   // prefetch under compute
    const float* abase = AsF + buf * 8192 + (rg * 32 + fr) * 128;
    const int s7 = fr & 7;
    #pragma unroll
    for (int c = 0; c < 8; ++c) {
      const int g0 = c * 4 + ks * 2;               // 16B granule of 8-float grp
      const float4 a0 = *(const float4*)(abase + ((g0 ^ s7) << 2));
      const float4 a1 = *(const float4*)(abase + (((g0 + 1) ^ s7) << 2));
      const float av[8] = {a0.x, a0.y, a0.z, a0.w, a1.x, a1.y, a1.z, a1.w};
      short8 ah, al;
      cvt8(av, ah, al);
      const int kc = step * 8 + c;                 // global 16-k chunk
      const short8 bh = bhB[(size_t)kc * 64];
      const short8 bl = blB[(size_t)kc * 64];
      acc = __builtin_amdgcn_mfma_f32_32x32x16_bf16(ah, bh, acc, 0, 0, 0);
      acc = __builtin_amdgcn_mfma_f32_32x32x16_bf16(ah, bl, acc, 0, 0, 0);
      acc = __builtin_amdgcn_mfma_f32_32x32x16_bf16(al, bh, acc, 0, 0, 0);
    }
    __syncthreads();   // drains DMA; next buf ready; protects read buf reuse
  }
  #undef STAGE

  // ---- epilogue: dump acc to LDS (alias As), add bias, pack bf16-split ----
  float* hsum = AsF;                         // [64][132] floats = 33.8 KB < 64 KB
  #pragma unroll
  for (int reg = 0; reg < 16; ++reg) {
    const int row = (reg & 3) + 8 * (reg >> 2) + 4 * ks;
    hsum[(rg * 32 + row) * 132 + wc * 32 + fr] = acc[reg];
  }
  __syncthreads();
  #pragma unroll
  for (int i = 0; i < 2; ++i) {
    const int task = t + 512 * i;            // 1024 tasks: 64 rows x 16 kc8
    const int row = task >> 4, kc8 = task & 15;
    float v[8];
    #pragma unroll
    for (int j = 0; j < 8; ++j)
      v[j] = hsum[row * 132 + kc8 * 8 + j] + bsh[kc8 * 8 + j];
    short8 hi8, lo8;
    cvt8(v, hi8, lo8);
    const int kc = kc8 >> 1, kh2 = kc8 & 1;
    const size_t idx = ((size_t)blockIdx.x * 2 + (row >> 5)) * 512 + kc * 64 +
                       ((row & 31) + 32 * kh2);
    ((short8*)hHi)[idx] = hi8;
    ((short8*)hLo)[idx] = lo8;
  }
}

// ---------------- K2: logits via MFMA + softmax + weighted col-sum -------------
// grid (256 row-tiles of 64, 3 segments), 512 threads = 8 waves. (verified)
__global__ __launch_bounds__(512, 2) void k2_mfma(const short* __restrict__ hHi,
                                                  const short* __restrict__ hLo,
                                                  const short* __restrict__ eHi,
                                                  const short* __restrict__ eLo,
                                                  const float* __restrict__ imp,
                                                  float* __restrict__ partials) {
  const int t = threadIdx.x;
  const int m0 = blockIdx.x * 64;
  const int seg = blockIdx.y;
  const int wave = t >> 6, lane = t & 63;
  const int wr = wave >> 2;
  const int wc = wave & 3;
  const int fr = lane & 31;
  const int hi = lane >> 5;

  __shared__ float redA[2][32][4];
  __shared__ float redB[2][32][4];
  __shared__ float ldsD[2][512];

  f32x16 acc[4] = {};

  const short8* pAh = (const short8*)hHi + ((m0 >> 5) + wr) * 512 + lane;
  const short8* pAl = (const short8*)hLo + ((m0 >> 5) + wr) * 512 + lane;
  const short8* pBh = (const short8*)eHi + (seg * 16 + wc * 4) * 512 + lane;
  const short8* pBl = (const short8*)eLo + (seg * 16 + wc * 4) * 512 + lane;

  #pragma unroll
  for (int kc = 0; kc < 8; ++kc) {
    const short8 ah = pAh[kc * 64];
    const short8 al = pAl[kc * 64];
    #pragma unroll
    for (int t2 = 0; t2 < 4; ++t2) {
      const short8 bh = pBh[t2 * 512 + kc * 64];
      const short8 bl = pBl[t2 * 512 + kc * 64];
      acc[t2] = __builtin_amdgcn_mfma_f32_32x32x16_bf16(ah, bh, acc[t2], 0, 0, 0);
      acc[t2] = __builtin_amdgcn_mfma_f32_32x32x16_bf16(ah, bl, acc[t2], 0, 0, 0);
      acc[t2] = __builtin_amdgcn_mfma_f32_32x32x16_bf16(al, bh, acc[t2], 0, 0, 0);
    }
  }

  // ---- row max (over 512 neurons) ----
  float mx[16];
  #pragma unroll
  for (int r = 0; r < 16; ++r) {
    float m = fmaxf(fmaxf(acc[0][r], acc[1][r]), fmaxf(acc[2][r], acc[3][r]));
    #pragma unroll
    for (int k = 1; k < 32; k <<= 1) m = fmaxf(m, __shfl_xor(m, k));
    mx[r] = m;
  }
  if (fr == 0) {
    #pragma unroll
    for (int r = 0; r < 16; ++r)
      redA[wr][(r & 3) + 8 * (r >> 2) + 4 * hi][wc] = mx[r];
  }
  __syncthreads();
  float M[16];
  #pragma unroll
  for (int r = 0; r < 16; ++r) {
    const int row = (r & 3) + 8 * (r >> 2) + 4 * hi;
    M[r] = fmaxf(fmaxf(redA[wr][row][0], redA[wr][row][1]),
                 fmaxf(redA[wr][row][2], redA[wr][row][3]));
  }

  // ---- exp + row sum ----
  float sm[16];
  #pragma unroll
  for (int r = 0; r < 16; ++r) {
    float s = 0.0f;
    #pragma unroll
    for (int t2 = 0; t2 < 4; ++t2) {
      const float p = __expf(acc[t2][r] - M[r]);
      acc[t2][r] = p;
      s += p;
    }
    #pragma unroll
    for (int k = 1; k < 32; k <<= 1) s += __shfl_xor(s, k);
    sm[r] = s;
  }
  if (fr == 0) {
    #pragma unroll
    for (int r = 0; r < 16; ++r)
      redB[wr][(r & 3) + 8 * (r >> 2) + 4 * hi][wc] = sm[r];
  }
  __syncthreads();
  float w[16];
  #pragma unroll
  for (int r = 0; r < 16; ++r) {
    const int row = (r & 3) + 8 * (r >> 2) + 4 * hi;
    const float S = (redB[wr][row][0] + redB[wr][row][1]) +
                    (redB[wr][row][2] + redB[wr][row][3]);
    w[r] = imp[m0 + wr * 32 + row] / S;
  }

  // ---- importance-weighted column partials (deterministic) ----
  #pragma unroll
  for (int t2 = 0; t2 < 4; ++t2) {
    float d = 0.0f;
    #pragma unroll
    for (int r = 0; r < 16; ++r) d = fmaf(acc[t2][r], w[r], d);
    d += __shfl_xor(d, 32);
    if (hi == 0) ldsD[wr][wc * 128 + t2 * 32 + fr] = d;
  }
  __syncthreads();
  partials[((size_t)seg * 256 + blockIdx.x) * 512 + t] = ldsD[0][t] + ldsD[1][t];
}

// ---------------- K3: sum partials (fixed order) + top-k + write ---------------
__global__ __launch_bounds__(256) void k3_topk(const float* __restrict__ partials,
                                               float* __restrict__ out) {
  const int b = blockIdx.x;
  const int seg = blockIdx.y;
  const int tid = threadIdx.x;
  const int K = (seg == 0) ? 8 : ((seg == 1) ? 4 : 6);

  __shared__ float v[512];
  __shared__ float wv[8];
  __shared__ int wi[8];
  __shared__ float redv[4];
  __shared__ int redi[4];

  const float* src = partials + ((size_t)seg * 256 + b * 64) * 512;
  float a0 = 0.f, a1 = 0.f, a2 = 0.f, a3 = 0.f;
  float b0 = 0.f, b1 = 0.f, b2 = 0.f, b3 = 0.f;
  for (int j = 0; j < 64; j += 4) {
    a0 += src[(size_t)(j + 0) * 512 + tid];
    a1 += src[(size_t)(j + 1) * 512 + tid];
    a2 += src[(size_t)(j + 2) * 512 + tid];
    a3 += src[(size_t)(j + 3) * 512 + tid];
    b0 += src[(size_t)(j + 0) * 512 + tid + 256];
    b1 += src[(size_t)(j + 1) * 512 + tid + 256];
    b2 += src[(size_t)(j + 2) * 512 + tid + 256];
    b3 += src[(size_t)(j + 3) * 512 + tid + 256];
  }
  v[tid] = (a0 + a1) + (a2 + a3);
  v[tid + 256] = (b0 + b1) + (b2 + b3);
  __syncthreads();

  for (int t = 0; t < K; ++t) {
    const float v0 = v[tid], v1 = v[tid + 256];
    float bv; int bi;
    if (v1 > v0) { bv = v1; bi = tid + 256; } else { bv = v0; bi = tid; }
    #pragma unroll
    for (int m = 1; m < 64; m <<= 1) {
      const float ov = __shfl_xor(bv, m);
      const int oi = __shfl_xor(bi, m);
      if (ov > bv || (ov == bv && oi < bi)) { bv = ov; bi = oi; }
    }
    if ((tid & 63) == 0) { redv[tid >> 6] = bv; redi[tid >> 6] = bi; }
    __syncthreads();
    if (tid == 0) {
      float best = redv[0]; int besti = redi[0];
      for (int q = 1; q < 4; ++q)
        if (redv[q] > best || (redv[q] == best && redi[q] < besti)) {
          best = redv[q]; besti = redi[q];
        }
      wv[t] = best; wi[t] = besti;
      v[besti] = -3.0e38f;
    }
    __syncthreads();
  }

  float s = 1e-8f;
  for (int t = 0; t < K; ++t) s += wv[t];

  const int slot0 = (seg == 0) ? 0 : ((seg == 1) ? 1 : 3);
  float* o0 = out + slot0 * (BATCH * NSEG) + b * NSEG;
  o0[tid] = 0.0f; o0[tid + 256] = 0.0f;
  float* o1 = nullptr;
  if (seg == 1) {
    o1 = out + 2 * (BATCH * NSEG) + b * NSEG;
    o1[tid] = 0.0f; o1[tid + 256] = 0.0f;
  }
  __syncthreads();
  if (tid < K) {
    const float val = wv[tid] / s;
    o0[wi[tid]] = val;
    if (seg == 1) o1[wi[tid]] = val;
  }
}

// -------------------------------- launch ---------------------------------------
extern "C" void kernel_launch(void* const* d_in, const int* in_sizes, int n_in,
                              void* d_out, int out_size, void* d_ws, size_t ws_size,
                              hipStream_t stream) {
  (void)in_sizes; (void)n_in; (void)out_size; (void)ws_size;
  const float* x    = (const float*)d_in[0];
  const float* imp  = (const float*)d_in[1];
  const float* W    = (const float*)d_in[2];
  const float* bias = (const float*)d_in[3];
  const float* emb  = (const float*)d_in[4];
  float* out = (float*)d_out;

  // workspace carve: partials (f32), then hHi | hLo | eHi | eLo | wHi | wLo (i16)
  float* partials = (float*)d_ws;                     // 768*512 f32
  short* hHi      = (short*)(partials + 768 * 512);   // 2097152 i16
  short* hLo      = hHi + 2097152;
  short* eHi      = hLo + 2097152;                    // 196608 i16
  short* eLo      = eHi + 196608;
  short* wHi      = eLo + 196608;                     // 262144 i16
  short* wLo      = wHi + 262144;

  k0_prep<<<512 + 1536, 64, 0, stream>>>(W, emb, wHi, wLo, eHi, eLo);
  k1_fused<<<ROWS / 64, 512, 0, stream>>>(x, wHi, wLo, bias, hHi, hLo);
  k2_mfma<<<dim3(ROWS / 64, 3), 512, 0, stream>>>(hHi, hLo, eHi, eLo, imp, partials);
  k3_topk<<<dim3(BATCH, 3), 256, 0, stream>>>(partials, out);
}

// Round 8
// 95.209 us; speedup vs baseline: 1.2893x; 1.2893x over previous
//
#include <hip/hip_runtime.h>
#include <hip/hip_bf16.h>

// Problem constants
#define BATCH 4
#define S_TOT 4096
#define ROWS (BATCH * S_TOT)   // 16384
#define DM 2048
#define DSP 128
#define NSEG 512               // neurons per segment; 3 segments

typedef short short8 __attribute__((ext_vector_type(8)));
typedef float f32x16 __attribute__((ext_vector_type(16)));

// float -> bf16(RNE) bits; also returns the fp32 value of the bf16 for residual
static __device__ inline short f2bf(float v, float& back) {
  unsigned u = __float_as_uint(v);
  unsigned r = u + 0x7FFFu + ((u >> 16) & 1u);
  unsigned short hs = (unsigned short)(r >> 16);
  back = __uint_as_float(((unsigned)hs) << 16);
  return (short)hs;
}

// packed f32x2 -> bf16x2 (hw instr). Lo term is exact residual of hi's value,
// so the split is correct regardless of cvt rounding mode.
static __device__ inline unsigned cvtpk2(float a, float b) {
  unsigned r;
  asm("v_cvt_pk_bf16_f32 %0, %1, %2" : "=v"(r) : "v"(a), "v"(b));
  return r;
}
static __device__ inline void cvt8(const float* v, short8& hi8, short8& lo8) {
  union { short8 s; unsigned u[4]; } H, L;
  #pragma unroll
  for (int w = 0; w < 4; ++w) {
    const float f0 = v[2 * w], f1 = v[2 * w + 1];
    const unsigned u = cvtpk2(f0, f1);
    const float b0 = __uint_as_float(u << 16);
    const float b1 = __uint_as_float(u & 0xffff0000u);
    L.u[w] = cvtpk2(f0 - b0, f1 - b1);
    H.u[w] = u;
  }
  hi8 = H.s; lo8 = L.s;
}

// global_load_lds, 16B per lane: per-lane global src, wave-uniform LDS dst
#define GLL16(gsrc, ldst)                                                       \
  __builtin_amdgcn_global_load_lds(                                             \
      (const __attribute__((address_space(1))) void*)(gsrc),                    \
      (__attribute__((address_space(3))) void*)(ldst), 16, 0, 0)

#define SBAR  __builtin_amdgcn_s_barrier()
#define SCHEDB __builtin_amdgcn_sched_barrier(0)

// Fragment layout for a [R][128-k] matrix, per split:
//   short8 index = rowblk*512 + kchunk*64 + lane,  lane=(row&31)+32*((k>>3)&1)
// For W (B-operand, [128 n][2048 k]): short8 index = (tile*128 + kchunk)*64 + lane,
//   lane=(n&31)+32*((k>>3)&1), tile=n>>5.

// ---------------- K0 fused: W-split pack (blocks 0..511) + emb norm pack -------
__global__ __launch_bounds__(64) void k0_prep(const float* __restrict__ W,
                                              const float* __restrict__ emb,
                                              short* __restrict__ wHi,
                                              short* __restrict__ wLo,
                                              short* __restrict__ eHi,
                                              short* __restrict__ eLo) {
  const int l = threadIdx.x;
  if (blockIdx.x < 512) {
    const int tc = blockIdx.x;
    const int t = tc >> 7, c = tc & 127;
    const int n = t * 32 + (l & 31);
    const int k = c * 16 + (l >> 5) * 8;
    const float4 a0 = *(const float4*)&W[(size_t)n * DM + k];
    const float4 a1 = *(const float4*)&W[(size_t)n * DM + k + 4];
    const float av[8] = {a0.x, a0.y, a0.z, a0.w, a1.x, a1.y, a1.z, a1.w};
    short8 hi8, lo8; float bk;
    #pragma unroll
    for (int e = 0; e < 8; ++e) {
      hi8[e] = f2bf(av[e], bk); lo8[e] = f2bf(av[e] - bk, bk);
    }
    const size_t idx = (size_t)tc * 64 + l;
    ((short8*)wHi)[idx] = hi8;
    ((short8*)wLo)[idx] = lo8;
  } else {
    const int row = blockIdx.x - 512;          // 0..1535
    __shared__ short sh[128], sl[128];
    float2 v = *(const float2*)&emb[row * 128 + l * 2];
    float ss = v.x * v.x + v.y * v.y;
    #pragma unroll
    for (int m = 32; m; m >>= 1) ss += __shfl_xor(ss, m);
    const float inv = 1.0f / fmaxf(sqrtf(ss), 1e-12f);
    float bk;
    const float ox = v.x * inv, oy = v.y * inv;
    sh[2 * l] = f2bf(ox, bk);     sl[2 * l] = f2bf(ox - bk, bk);
    sh[2 * l + 1] = f2bf(oy, bk); sl[2 * l + 1] = f2bf(oy - bk, bk);
    __syncthreads();
    if (l < 32) {
      const int split = l >> 4, kc = (l >> 1) & 7, kh = l & 1;
      const short* src = (split ? sl : sh) + kc * 16 + kh * 8;
      const short8 val = *(const short8*)src;
      const size_t idx = (size_t)(row >> 5) * 4096 + kc * 512 +
                         ((row & 31) + 32 * kh) * 8;
      *(short8*)((split ? eLo : eHi) + idx) = val;
    }
  }
}

// ---------------- K1: h-partial = x @ W^T, counted-vmcnt GLL pipeline ----------
// grid (128 M-tiles, 2 K-halves), 512 thr = 8 waves. BM=128 BN=128 BK=32.
// Per step, per wave: 4 global_load_lds (2 A rows-slab, 2 B combos).
// Loop: vmcnt(4)->barrier->ds_read->lgkmcnt(0)->barrier->stage(+2)->cvt+MFMA.
// Never drains vmcnt to 0 in steady state (T3+T4). Raw s_barrier only.
#define NSTEP 32
__global__ __launch_bounds__(512, 2) void k1_mfma(const float* __restrict__ x,
                                                  const short* __restrict__ wHi,
                                                  const short* __restrict__ wLo,
                                                  float* __restrict__ hPart) {
  __shared__ __align__(16) char lbuf[2][32768];   // per buf: A 16KB | B 16KB
  const int t = threadIdx.x;
  const int wave = t >> 6, lane = t & 63;
  const int fr = lane & 31, ks = lane >> 5;
  const int rg = wave >> 1, cg = wave & 1;        // rows rg*32, cols cg*64
  const int m0 = blockIdx.x * 128;
  const int y  = blockIdx.y;                      // K-half

  // A staging: instr a in {0,1}: rows wave*16+a*8+(lane>>3); XOR-swizzled src
  const int ar0 = wave * 16 + (lane >> 3);
  const int ar1 = ar0 + 8;
  const float* asrc0 = x + (size_t)(m0 + ar0) * DM + y * 1024 +
                       (((lane & 7) ^ (ar0 & 7)) << 2);
  const float* asrc1 = x + (size_t)(m0 + ar1) * DM + y * 1024 +
                       (((lane & 7) ^ (ar1 & 7)) << 2);
  // B staging: combo = tile*4 + cl*2 + sp = wave*2 + i
  const int c0 = wave * 2, c1 = wave * 2 + 1;
  const short* bsrc0 = ((c0 & 1) ? wLo : wHi) +
                       (((size_t)(c0 >> 2) * 128 + y * 64) * 64 + lane) * 8;
  const short* bsrc1 = ((c1 & 1) ? wLo : wHi) +
                       (((size_t)(c1 >> 2) * 128 + y * 64) * 64 + lane) * 8;
  const int bcl0 = (c0 >> 1) & 1, bcl1 = (c1 >> 1) & 1;

  #define STAGE(buf, s)                                                         \
    {                                                                           \
      GLL16(asrc0 + (s) * 32, lbuf[buf] + wave * 2048);                         \
      GLL16(asrc1 + (s) * 32, lbuf[buf] + wave * 2048 + 1024);                  \
      GLL16(bsrc0 + ((s) * 2 + bcl0) * 512, lbuf[buf] + 16384 + c0 * 1024);     \
      GLL16(bsrc1 + ((s) * 2 + bcl1) * 512, lbuf[buf] + 16384 + c1 * 1024);     \
    }

  f32x16 acc0 = {}, acc1 = {};
  const int arow = rg * 32 + fr;
  const int r7 = arow & 7;

  STAGE(0, 0);
  STAGE(1, 1);

  #pragma unroll 1
  for (int step = 0; step < NSTEP; ++step) {
    const int buf = step & 1;
    if (step != NSTEP - 1) {
      asm volatile("s_waitcnt vmcnt(4)" ::: "memory");   // cur buf done; next in flight
    } else {
      asm volatile("s_waitcnt vmcnt(0)" ::: "memory");   // final buf
    }
    SBAR; SCHEDB;

    const float* Arow = (const float*)(lbuf[buf]) + arow * 32;
    const short8* Bb  = (const short8*)(lbuf[buf] + 16384);
    // ds_read A: 4x b128 (2 chunks x 2)
    float4 a00 = *(const float4*)(Arow + (((0 + ks * 2 + 0) ^ r7) << 2));
    float4 a01 = *(const float4*)(Arow + (((0 + ks * 2 + 1) ^ r7) << 2));
    float4 a10 = *(const float4*)(Arow + (((4 + ks * 2 + 0) ^ r7) << 2));
    float4 a11 = *(const float4*)(Arow + (((4 + ks * 2 + 1) ^ r7) << 2));
    // ds_read B: 8x b128  [cl][tt][sp], tile = cg*2+tt
    short8 b000 = Bb[((cg * 2 + 0) * 4 + 0 * 2 + 0) * 64 + lane];
    short8 b001 = Bb[((cg * 2 + 0) * 4 + 0 * 2 + 1) * 64 + lane];
    short8 b010 = Bb[((cg * 2 + 1) * 4 + 0 * 2 + 0) * 64 + lane];
    short8 b011 = Bb[((cg * 2 + 1) * 4 + 0 * 2 + 1) * 64 + lane];
    short8 b100 = Bb[((cg * 2 + 0) * 4 + 1 * 2 + 0) * 64 + lane];
    short8 b101 = Bb[((cg * 2 + 0) * 4 + 1 * 2 + 1) * 64 + lane];
    short8 b110 = Bb[((cg * 2 + 1) * 4 + 1 * 2 + 0) * 64 + lane];
    short8 b111 = Bb[((cg * 2 + 1) * 4 + 1 * 2 + 1) * 64 + lane];
    asm volatile("s_waitcnt lgkmcnt(0)" ::: "memory");
    SCHEDB;
    SBAR; SCHEDB;        // all waves' reads landed -> safe to overwrite buf

    if (step + 2 < NSTEP) STAGE(buf, step + 2);

    // chunk 0
    {
      const float av[8] = {a00.x, a00.y, a00.z, a00.w, a01.x, a01.y, a01.z, a01.w};
      short8 ah, al; cvt8(av, ah, al);
      acc0 = __builtin_amdgcn_mfma_f32_32x32x16_bf16(ah, b000, acc0, 0, 0, 0);
      acc0 = __builtin_amdgcn_mfma_f32_32x32x16_bf16(ah, b001, acc0, 0, 0, 0);
      acc0 = __builtin_amdgcn_mfma_f32_32x32x16_bf16(al, b000, acc0, 0, 0, 0);
      acc1 = __builtin_amdgcn_mfma_f32_32x32x16_bf16(ah, b010, acc1, 0, 0, 0);
      acc1 = __builtin_amdgcn_mfma_f32_32x32x16_bf16(ah, b011, acc1, 0, 0, 0);
      acc1 = __builtin_amdgcn_mfma_f32_32x32x16_bf16(al, b010, acc1, 0, 0, 0);
    }
    // chunk 1
    {
      const float av[8] = {a10.x, a10.y, a10.z, a10.w, a11.x, a11.y, a11.z, a11.w};
      short8 ah, al; cvt8(av, ah, al);
      acc0 = __builtin_amdgcn_mfma_f32_32x32x16_bf16(ah, b100, acc0, 0, 0, 0);
      acc0 = __builtin_amdgcn_mfma_f32_32x32x16_bf16(ah, b101, acc0, 0, 0, 0);
      acc0 = __builtin_amdgcn_mfma_f32_32x32x16_bf16(al, b100, acc0, 0, 0, 0);
      acc1 = __builtin_amdgcn_mfma_f32_32x32x16_bf16(ah, b110, acc1, 0, 0, 0);
      acc1 = __builtin_amdgcn_mfma_f32_32x32x16_bf16(ah, b111, acc1, 0, 0, 0);
      acc1 = __builtin_amdgcn_mfma_f32_32x32x16_bf16(al, b110, acc1, 0, 0, 0);
    }
  }
  #undef STAGE

  // epilogue: store fp32 partials (no bias; k1c adds it once)
  float* hp = hPart + (size_t)y * ROWS * DSP;
  #pragma unroll
  for (int reg = 0; reg < 16; ++reg) {
    const int row = (reg & 3) + 8 * (reg >> 2) + 4 * ks;
    const size_t base = (size_t)(m0 + rg * 32 + row) * DSP + cg * 64;
    hp[base + fr]      = acc0[reg];
    hp[base + 32 + fr] = acc1[reg];
  }
}

// ---------------- K1c: sum K-halves + bias, split to bf16 hi/lo, pack ----------
__global__ __launch_bounds__(256) void k1c_pack(const float* __restrict__ hPart,
                                                const float* __restrict__ bias,
                                                short* __restrict__ hHi,
                                                short* __restrict__ hLo) {
  const int gid = blockIdx.x * 256 + threadIdx.x;   // 262144 tasks
  const int row = gid >> 4, kc8 = gid & 15;
  const float* p0 = hPart + (size_t)row * 128 + kc8 * 8;
  const float* p1 = p0 + (size_t)ROWS * 128;
  const float4 a0 = *(const float4*)p0, a1 = *(const float4*)(p0 + 4);
  const float4 b0 = *(const float4*)p1, b1 = *(const float4*)(p1 + 4);
  const float4 c0 = *(const float4*)&bias[kc8 * 8];
  const float4 c1 = *(const float4*)&bias[kc8 * 8 + 4];
  const float v[8] = {a0.x + b0.x + c0.x, a0.y + b0.y + c0.y,
                      a0.z + b0.z + c0.z, a0.w + b0.w + c0.w,
                      a1.x + b1.x + c1.x, a1.y + b1.y + c1.y,
                      a1.z + b1.z + c1.z, a1.w + b1.w + c1.w};
  short8 hi8, lo8;
  cvt8(v, hi8, lo8);
  const int kc = kc8 >> 1, kh = kc8 & 1;
  const size_t idx = (size_t)(row >> 5) * 512 + kc * 64 + ((row & 31) + 32 * kh);
  ((short8*)hHi)[idx] = hi8;
  ((short8*)hLo)[idx] = lo8;
}

// ---------------- K2: logits via MFMA + softmax + weighted col-sum -------------
// grid (256 row-tiles of 64, 3 segments), 512 threads = 8 waves. (verified)
__global__ __launch_bounds__(512, 2) void k2_mfma(const short* __restrict__ hHi,
                                                  const short* __restrict__ hLo,
                                                  const short* __restrict__ eHi,
                                                  const short* __restrict__ eLo,
                                                  const float* __restrict__ imp,
                                                  float* __restrict__ partials) {
  const int t = threadIdx.x;
  const int m0 = blockIdx.x * 64;
  const int seg = blockIdx.y;
  const int wave = t >> 6, lane = t & 63;
  const int wr = wave >> 2;
  const int wc = wave & 3;
  const int fr = lane & 31;
  const int hi = lane >> 5;

  __shared__ float redA[2][32][4];
  __shared__ float redB[2][32][4];
  __shared__ float ldsD[2][512];

  f32x16 acc[4] = {};

  const short8* pAh = (const short8*)hHi + ((m0 >> 5) + wr) * 512 + lane;
  const short8* pAl = (const short8*)hLo + ((m0 >> 5) + wr) * 512 + lane;
  const short8* pBh = (const short8*)eHi + (seg * 16 + wc * 4) * 512 + lane;
  const short8* pBl = (const short8*)eLo + (seg * 16 + wc * 4) * 512 + lane;

  #pragma unroll
  for (int kc = 0; kc < 8; ++kc) {
    const short8 ah = pAh[kc * 64];
    const short8 al = pAl[kc * 64];
    #pragma unroll
    for (int t2 = 0; t2 < 4; ++t2) {
      const short8 bh = pBh[t2 * 512 + kc * 64];
      const short8 bl = pBl[t2 * 512 + kc * 64];
      acc[t2] = __builtin_amdgcn_mfma_f32_32x32x16_bf16(ah, bh, acc[t2], 0, 0, 0);
      acc[t2] = __builtin_amdgcn_mfma_f32_32x32x16_bf16(ah, bl, acc[t2], 0, 0, 0);
      acc[t2] = __builtin_amdgcn_mfma_f32_32x32x16_bf16(al, bh, acc[t2], 0, 0, 0);
    }
  }

  float mx[16];
  #pragma unroll
  for (int r = 0; r < 16; ++r) {
    float m = fmaxf(fmaxf(acc[0][r], acc[1][r]), fmaxf(acc[2][r], acc[3][r]));
    #pragma unroll
    for (int k = 1; k < 32; k <<= 1) m = fmaxf(m, __shfl_xor(m, k));
    mx[r] = m;
  }
  if (fr == 0) {
    #pragma unroll
    for (int r = 0; r < 16; ++r)
      redA[wr][(r & 3) + 8 * (r >> 2) + 4 * hi][wc] = mx[r];
  }
  __syncthreads();
  float M[16];
  #pragma unroll
  for (int r = 0; r < 16; ++r) {
    const int row = (r & 3) + 8 * (r >> 2) + 4 * hi;
    M[r] = fmaxf(fmaxf(redA[wr][row][0], redA[wr][row][1]),
                 fmaxf(redA[wr][row][2], redA[wr][row][3]));
  }

  float sm[16];
  #pragma unroll
  for (int r = 0; r < 16; ++r) {
    float s = 0.0f;
    #pragma unroll
    for (int t2 = 0; t2 < 4; ++t2) {
      const float p = __expf(acc[t2][r] - M[r]);
      acc[t2][r] = p;
      s += p;
    }
    #pragma unroll
    for (int k = 1; k < 32; k <<= 1) s += __shfl_xor(s, k);
    sm[r] = s;
  }
  if (fr == 0) {
    #pragma unroll
    for (int r = 0; r < 16; ++r)
      redB[wr][(r & 3) + 8 * (r >> 2) + 4 * hi][wc] = sm[r];
  }
  __syncthreads();
  float w[16];
  #pragma unroll
  for (int r = 0; r < 16; ++r) {
    const int row = (r & 3) + 8 * (r >> 2) + 4 * hi;
    const float S = (redB[wr][row][0] + redB[wr][row][1]) +
                    (redB[wr][row][2] + redB[wr][row][3]);
    w[r] = imp[m0 + wr * 32 + row] / S;
  }

  #pragma unroll
  for (int t2 = 0; t2 < 4; ++t2) {
    float d = 0.0f;
    #pragma unroll
    for (int r = 0; r < 16; ++r) d = fmaf(acc[t2][r], w[r], d);
    d += __shfl_xor(d, 32);
    if (hi == 0) ldsD[wr][wc * 128 + t2 * 32 + fr] = d;
  }
  __syncthreads();
  partials[((size_t)seg * 256 + blockIdx.x) * 512 + t] = ldsD[0][t] + ldsD[1][t];
}

// ---------------- K3: sum partials (fixed order) + top-k + write ---------------
__global__ __launch_bounds__(256) void k3_topk(const float* __restrict__ partials,
                                               float* __restrict__ out) {
  const int b = blockIdx.x;
  const int seg = blockIdx.y;
  const int tid = threadIdx.x;
  const int K = (seg == 0) ? 8 : ((seg == 1) ? 4 : 6);

  __shared__ float v[512];
  __shared__ float wv[8];
  __shared__ int wi[8];
  __shared__ float redv[4];
  __shared__ int redi[4];

  const float* src = partials + ((size_t)seg * 256 + b * 64) * 512;
  float a0 = 0.f, a1 = 0.f, a2 = 0.f, a3 = 0.f;
  float b0 = 0.f, b1 = 0.f, b2 = 0.f, b3 = 0.f;
  for (int j = 0; j < 64; j += 4) {
    a0 += src[(size_t)(j + 0) * 512 + tid];
    a1 += src[(size_t)(j + 1) * 512 + tid];
    a2 += src[(size_t)(j + 2) * 512 + tid];
    a3 += src[(size_t)(j + 3) * 512 + tid];
    b0 += src[(size_t)(j + 0) * 512 + tid + 256];
    b1 += src[(size_t)(j + 1) * 512 + tid + 256];
    b2 += src[(size_t)(j + 2) * 512 + tid + 256];
    b3 += src[(size_t)(j + 3) * 512 + tid + 256];
  }
  v[tid] = (a0 + a1) + (a2 + a3);
  v[tid + 256] = (b0 + b1) + (b2 + b3);
  __syncthreads();

  for (int t = 0; t < K; ++t) {
    const float v0 = v[tid], v1 = v[tid + 256];
    float bv; int bi;
    if (v1 > v0) { bv = v1; bi = tid + 256; } else { bv = v0; bi = tid; }
    #pragma unroll
    for (int m = 1; m < 64; m <<= 1) {
      const float ov = __shfl_xor(bv, m);
      const int oi = __shfl_xor(bi, m);
      if (ov > bv || (ov == bv && oi < bi)) { bv = ov; bi = oi; }
    }
    if ((tid & 63) == 0) { redv[tid >> 6] = bv; redi[tid >> 6] = bi; }
    __syncthreads();
    if (tid == 0) {
      float best = redv[0]; int besti = redi[0];
      for (int q = 1; q < 4; ++q)
        if (redv[q] > best || (redv[q] == best && redi[q] < besti)) {
          best = redv[q]; besti = redi[q];
        }
      wv[t] = best; wi[t] = besti;
      v[besti] = -3.0e38f;
    }
    __syncthreads();
  }

  float s = 1e-8f;
  for (int t = 0; t < K; ++t) s += wv[t];

  const int slot0 = (seg == 0) ? 0 : ((seg == 1) ? 1 : 3);
  float* o0 = out + slot0 * (BATCH * NSEG) + b * NSEG;
  o0[tid] = 0.0f; o0[tid + 256] = 0.0f;
  float* o1 = nullptr;
  if (seg == 1) {
    o1 = out + 2 * (BATCH * NSEG) + b * NSEG;
    o1[tid] = 0.0f; o1[tid + 256] = 0.0f;
  }
  __syncthreads();
  if (tid < K) {
    const float val = wv[tid] / s;
    o0[wi[tid]] = val;
    if (seg == 1) o1[wi[tid]] = val;
  }
}

// -------------------------------- launch ---------------------------------------
extern "C" void kernel_launch(void* const* d_in, const int* in_sizes, int n_in,
                              void* d_out, int out_size, void* d_ws, size_t ws_size,
                              hipStream_t stream) {
  (void)in_sizes; (void)n_in; (void)out_size; (void)ws_size;
  const float* x    = (const float*)d_in[0];
  const float* imp  = (const float*)d_in[1];
  const float* W    = (const float*)d_in[2];
  const float* bias = (const float*)d_in[3];
  const float* emb  = (const float*)d_in[4];
  float* out = (float*)d_out;

  // workspace carve: partials f32 | hHi hLo eHi eLo wHi wLo (i16) | hPart f32 x2
  float* partials = (float*)d_ws;                     // 393216 f32
  short* hHi      = (short*)(partials + 393216);      // 2097152 i16
  short* hLo      = hHi + 2097152;
  short* eHi      = hLo + 2097152;                    // 196608 i16
  short* eLo      = eHi + 196608;
  short* wHi      = eLo + 196608;                     // 262144 i16
  short* wLo      = wHi + 262144;
  float* hPart    = (float*)(wLo + 262144);           // 2 x 2097152 f32

  k0_prep<<<512 + 1536, 64, 0, stream>>>(W, emb, wHi, wLo, eHi, eLo);
  k1_mfma<<<dim3(ROWS / 128, 2), 512, 0, stream>>>(x, wHi, wLo, hPart);
  k1c_pack<<<1024, 256, 0, stream>>>(hPart, bias, hHi, hLo);
  k2_mfma<<<dim3(ROWS / 64, 3), 512, 0, stream>>>(hHi, hLo, eHi, eLo, imp, partials);
  k3_topk<<<dim3(BATCH, 3), 256, 0, stream>>>(partials, out);
}